// Round 6
// baseline (1511.559 us; speedup 1.0000x reference)
//
#include <hip/hip_runtime.h>

// ---------------- problem constants ----------------
#define BB 8
#define NQ 300
#define NTQ 50
#define NLAY 6
#define S_TOTAL 20197
#define ROWS (BB*NQ)        // 2400
#define MVAL (BB*S_TOTAL)   // 161576

typedef unsigned short u16;
typedef unsigned int u32;
typedef __bf16 v8bf __attribute__((ext_vector_type(8)));
typedef float f32x4 __attribute__((ext_vector_type(4)));

__device__ __forceinline__ u16 f2b(float f) {
    u32 u = __float_as_uint(f);
    u32 r = (u + 0x7fffu + ((u >> 16) & 1u)) >> 16;
    return (u16)r;
}
__device__ __forceinline__ u32 pk2(float lo, float hi) {
    return (u32)f2b(lo) | ((u32)f2b(hi) << 16);
}

// async global->LDS 16B/lane. LDS dest must be wave-uniform base + lane*16;
// global source address is per-lane (m173).
#define ASYNC_CP16(dst_lds, src_g) \
    __builtin_amdgcn_global_load_lds((const __attribute__((address_space(1))) u32*)(src_g), \
                                     (__attribute__((address_space(3))) u32*)(dst_lds), 16, 0, 0)

// ---------------- weight transpose (f32 -> bf16) + bias pack ----------------
// wt layout per layer (element offsets, layer stride 884736):
//   [0) offa_t 384x256 | [98304) wv_t 256x256 | [163840) wout_t 256x256
//   [229376) wl1_t 1024x256 | [491520) wl2_t 256x1024 | [753664) wqk_t 512x256
// bias f32 per layer (stride 2688): boffa[0) bv[384) bout[640) bl1[896) bl2[1920) bqk[2176)
__global__ void transpose_pack(
    const float* Woff, const float* Wa, const float* Wv, const float* Wout,
    const float* Wl1, const float* Wl2, const float* Wq, const float* Wk,
    const float* boff, const float* ba, const float* bvp, const float* bout,
    const float* bl1, const float* bl2, const float* bq, const float* bk,
    u16* wt, float* bias)
{
    int idx = blockIdx.x * 256 + threadIdx.x;
    if (idx < 5308416) {
        int l = idx / 884736;
        int o = idx % 884736;
        float v;
        if (o < 98304) { int n = o >> 8, k = o & 255;
            v = (n < 256) ? Woff[l*65536 + k*256 + n] : Wa[l*32768 + k*128 + (n-256)];
        } else if (o < 163840) { int o2 = o - 98304; int n = o2 >> 8, k = o2 & 255;
            v = Wv[l*65536 + k*256 + n];
        } else if (o < 229376) { int o2 = o - 163840; int n = o2 >> 8, k = o2 & 255;
            v = Wout[l*65536 + k*256 + n];
        } else if (o < 491520) { int o2 = o - 229376; int n = o2 >> 8, k = o2 & 255;
            v = Wl1[l*262144 + k*1024 + n];
        } else if (o < 753664) { int o2 = o - 491520; int n = o2 >> 10, k = o2 & 1023;
            v = Wl2[l*262144 + k*256 + n];
        } else { int o2 = o - 753664; int n = o2 >> 8, k = o2 & 255;
            v = (n < 256) ? Wq[l*65536 + k*256 + n] : Wk[l*65536 + k*256 + (n-256)];
        }
        wt[idx] = f2b(v);
    } else {
        int i2 = idx - 5308416;
        if (i2 < 16128) {
            int l = i2 / 2688, o = i2 % 2688;
            float v;
            if (o < 256)       v = boff[l*256 + o];
            else if (o < 384)  v = ba  [l*128 + (o-256)];
            else if (o < 640)  v = bvp [l*256 + (o-384)];
            else if (o < 896)  v = bout[l*256 + (o-640)];
            else if (o < 1920) v = bl1 [l*1024 + (o-896)];
            else if (o < 2176) v = bl2 [l*256 + (o-1920)];
            else if (o < 2432) v = bq  [l*256 + (o-2176)];
            else               v = bk  [l*256 + (o-2432)];
            bias[i2] = v;
        }
    }
}

// ---------------- setup: p_pos, proposals init, layer-0 q, p_ref out, tq pack ----
__global__ void setup_kernel(const float* tgt, const float* refp, float* prop,
                             u16* q_b, float* ppos, u16* tq, float* out_pref)
{
    int row = blockIdx.x, t = threadIdx.x;
    if (row < ROWS) {
        int b = row / NQ, q = row % NQ;
        int k = t >> 6, rem = t & 63, j = rem >> 1;
        float pr = refp[(b*350 + q)*4 + k];
        float dimt = powf(10000.0f, (float)j * (1.0f/32.0f));
        float arg = pr * 6.283185307179586f / dimt;
        float pe = (rem & 1) ? cosf(arg) : sinf(arg);
        ppos[row*256 + t] = pe;
        float pv = tgt[(b*350 + q)*256 + t];
        prop[row*256 + t] = pv;
        q_b[row*256 + t] = f2b(pv + pe);
        if (t < 4) out_pref[row*4 + t] = refp[(b*350 + q)*4 + t];
    } else {
        int r2 = row - ROWS;           // 0..399
        int b = r2 / NTQ, qq = r2 % NTQ;
        tq[r2*256 + t] = f2b(tgt[(b*350 + NQ + qq)*256 + t]);
    }
}

// ---------------- bf16 MFMA GEMM (64x128 tile, dbuf) for small-M GEMMs --------
__global__ __launch_bounds__(256) void gemm_bt64(
    const u16* __restrict__ A, const u16* __restrict__ Bt,
    const float* __restrict__ bias, void* __restrict__ Cout,
    int M, int N, int K, int flags)
{
    __shared__ __align__(16) u16 As[2][64*32];
    __shared__ __align__(16) u16 Bs[2][128*32];
    int tid = threadIdx.x;
    int lane = tid & 63, wave = tid >> 6;
    int bm = blockIdx.y * 64, bn = blockIdx.x * 128;
    int wm = (wave >> 1) * 32, wn = (wave & 1) * 64;
    f32x4 acc[2][4] = {};
    int r = tid >> 2, c = (tid & 3) * 8;
    const u16* Ap0 = A  + (long)min(bm + r,      M-1) * K + c;
    const u16* Bp0 = Bt + (long)min(bn + r,      N-1) * K + c;
    const u16* Bp1 = Bt + (long)min(bn + r + 64, N-1) * K + c;
    int fr = lane & 15, fk = (lane >> 4) * 8;

    auto STG = [&](int bi, int k0) {
        ASYNC_CP16(&As[bi][tid*8],         Ap0 + k0);
        ASYNC_CP16(&Bs[bi][tid*8],         Bp0 + k0);
        ASYNC_CP16(&Bs[bi][64*32 + tid*8], Bp1 + k0);
    };
    STG(0, 0);
    asm volatile("s_waitcnt vmcnt(0)" ::: "memory");
    __syncthreads();
    int cur = 0;
    for (int k0 = 0; k0 < K; k0 += 32) {
        if (k0 + 32 < K) STG(cur ^ 1, k0 + 32);
        v8bf af[2], bf[4];
        #pragma unroll
        for (int i = 0; i < 2; ++i) af[i] = *(const v8bf*)&As[cur][(wm + i*16 + fr)*32 + fk];
        #pragma unroll
        for (int j = 0; j < 4; ++j) bf[j] = *(const v8bf*)&Bs[cur][(wn + j*16 + fr)*32 + fk];
        #pragma unroll
        for (int i = 0; i < 2; ++i)
            #pragma unroll
            for (int j = 0; j < 4; ++j)
                acc[i][j] = __builtin_amdgcn_mfma_f32_16x16x32_bf16(af[i], bf[j], acc[i][j], 0, 0, 0);
        asm volatile("s_waitcnt vmcnt(0)" ::: "memory");
        __syncthreads();
        cur ^= 1;
    }
    int cq = lane >> 4, cn = lane & 15;
    #pragma unroll
    for (int i = 0; i < 2; ++i) {
        #pragma unroll
        for (int j = 0; j < 4; ++j) {
            int col = bn + wn + j*16 + cn;
            float bv_ = bias ? bias[col] : 0.0f;
            #pragma unroll
            for (int rr = 0; rr < 4; ++rr) {
                int m = bm + wm + i*16 + cq*4 + rr;
                if (m < M) {
                    float v = acc[i][j][rr] + bv_;
                    if (flags & 1) v = fmaxf(v, 0.0f);
                    if (flags & 2) ((u16*)Cout)[(long)m*N + col] = f2b(v);
                    else           ((float*)Cout)[(long)m*N + col] = v;
                }
            }
        }
    }
}

// ---------------- batched value GEMM v4: register-A, zero-LDS, barrier-free ----
// value_l = src @ Wv_l^T + bv_l for l=0..5, converting src f32->bf16 in-register
// (src_convert kernel deleted; src_b buffer deleted).
// Grid 1263; block owns 128 A-rows; wave owns 32 rows held in VGPRs for the
// whole kernel (16 x v8bf = 64 VGPR). B fragments load global->register
// directly (768 KB total, L2-resident, shared by all blocks; 16 MFMA per
// 8 x 16B loads). NO LDS, NO barriers -- only per-wave vmcnt scheduling.
// ~190 VGPR -> 2 waves/SIMD (8 waves/CU).
__global__ __launch_bounds__(256, 2) void gemm_value6_v4(
    const float* __restrict__ srcf, const u16* __restrict__ wtall,
    const float* __restrict__ biasall, u16* __restrict__ Cout)
{
    int tid = threadIdx.x;
    int lane = tid & 63, wave = tid >> 6;
    int fr = lane & 15, q = lane >> 4;
    long rowb = (long)blockIdx.x * 128 + wave*32;     // wave's 32 rows

    // ---- load + convert A rows into registers (held for entire kernel) ----
    const float* Ar0 = srcf + (long)min(rowb + fr,      (long)(MVAL-1))*256 + q*8;
    const float* Ar1 = srcf + (long)min(rowb + 16 + fr, (long)(MVAL-1))*256 + q*8;
    v8bf a0[8], a1[8];
    #pragma unroll
    for (int ks = 0; ks < 8; ++ks) {
        float4 lo = *(const float4*)(Ar0 + ks*32);
        float4 hi = *(const float4*)(Ar0 + ks*32 + 4);
        uint4 pk = make_uint4(pk2(lo.x,lo.y), pk2(lo.z,lo.w), pk2(hi.x,hi.y), pk2(hi.z,hi.w));
        a0[ks] = *(v8bf*)&pk;
        float4 lo1 = *(const float4*)(Ar1 + ks*32);
        float4 hi1 = *(const float4*)(Ar1 + ks*32 + 4);
        uint4 pk1 = make_uint4(pk2(lo1.x,lo1.y), pk2(lo1.z,lo1.w), pk2(hi1.x,hi1.y), pk2(hi1.z,hi1.w));
        a1[ks] = *(v8bf*)&pk1;
    }

    // per-lane B fragment base: frag(z,half,ks,j) at
    //   wtall + z*884736 + 98304 + (half*128 + j*16 + fr)*256 + ks*32 + q*8
    const u16* Bbase = wtall + 98304 + (size_t)fr*256 + q*8;

    for (int t = 0; t < 12; ++t) {
        int z = t >> 1, half = t & 1;
        const u16* Bt = Bbase + (size_t)z*884736 + (size_t)(half*128)*256;
        u16* Cz = Cout + (size_t)z*((size_t)MVAL*256);
        const float* bs = biasall + z*2688 + 384 + half*128 + fr;
        float bc[8];
        #pragma unroll
        for (int j = 0; j < 8; ++j) bc[j] = bs[j*16];

        f32x4 acc0[8] = {}, acc1[8] = {};
        #pragma unroll
        for (int ks = 0; ks < 8; ++ks) {
            v8bf bf[8];
            #pragma unroll
            for (int j = 0; j < 8; ++j)
                bf[j] = *(const v8bf*)(Bt + (size_t)(j*16)*256 + ks*32);
            #pragma unroll
            for (int j = 0; j < 8; ++j) {
                acc0[j] = __builtin_amdgcn_mfma_f32_16x16x32_bf16(a0[ks], bf[j], acc0[j], 0, 0, 0);
                acc1[j] = __builtin_amdgcn_mfma_f32_16x16x32_bf16(a1[ks], bf[j], acc1[j], 0, 0, 0);
            }
        }
        // epilogue: C/D layout col=lane&15 (fr), row=(lane>>4)*4+rr
        #pragma unroll
        for (int j = 0; j < 8; ++j) {
            int col = half*128 + j*16 + fr;
            #pragma unroll
            for (int rr = 0; rr < 4; ++rr) {
                long m0 = rowb + q*4 + rr;
                long m1 = rowb + 16 + q*4 + rr;
                if (m0 < MVAL) Cz[m0*256 + col] = f2b(acc0[j][rr] + bc[j]);
                if (m1 < MVAL) Cz[m1*256 + col] = f2b(acc1[j][rr] + bc[j]);
            }
        }
    }
}

// ---------------- fused softmax+locations (LDS) + vectorized bilinear gather ----
__global__ __launch_bounds__(256) void sample_fused(
    const u16* __restrict__ value, const float* __restrict__ offatt,
    const float* __restrict__ refp, const float* __restrict__ svr,
    u16* __restrict__ sampout)
{
    int row = blockIdx.x, t = threadIdx.x;
    int b = row / NQ, q = row % NQ;
    __shared__ float lg[128], awl[128], sxl[128], syl[128];
    const int WL[4] = {152,76,38,19}, HL[4] = {100,50,25,13}, LS[4] = {0,15200,19000,19950};

    if (t < 128) lg[t] = offatt[row*384 + 256 + t];
    __syncthreads();
    if (t < 128) {
        int h = t >> 4, s = t & 15, lvl = s >> 2, pp = s & 3;
        int gb = h << 4;
        float mx = -1e30f;
        for (int i = 0; i < 16; ++i) mx = fmaxf(mx, lg[gb + i]);
        float sm = 0.f;
        for (int i = 0; i < 16; ++i) sm += expf(lg[gb + i] - mx);
        awl[t] = expf(lg[t] - mx) / sm;
        float rx = refp[(b*350+q)*4 + 0] * svr[(b*4+lvl)*2 + 0];
        float ry = refp[(b*350+q)*4 + 1] * svr[(b*4+lvl)*2 + 1];
        float rw = refp[(b*350+q)*4 + 2] * svr[(b*4+lvl)*2 + 0];
        float rh = refp[(b*350+q)*4 + 3] * svr[(b*4+lvl)*2 + 1];
        float ox = offatt[row*384 + h*32 + lvl*8 + pp*2 + 0];
        float oy = offatt[row*384 + h*32 + lvl*8 + pp*2 + 1];
        sxl[t] = (rx + ox * 0.25f * rw * 0.5f) * (float)WL[lvl] - 0.5f;
        syl[t] = (ry + oy * 0.25f * rh * 0.5f) * (float)HL[lvl] - 0.5f;
    }
    __syncthreads();

    int lane = t & 63, wv = t >> 6;
    int g = lane >> 3, e = lane & 7;       // group handles one corner; lane -> 4 channels
    for (int hh = 0; hh < 2; ++hh) {
        int h = wv*2 + hh;
        float a0 = 0.f, a1 = 0.f, a2 = 0.f, a3 = 0.f;
        #pragma unroll
        for (int it = 0; it < 8; ++it) {
            int task = it*8 + g;           // 0..63 = s*4 + corner
            int s = task >> 2, cc = task & 3;
            int cx = cc & 1, cy = cc >> 1;
            int lvl = s >> 2;
            float x = sxl[h*16 + s], y2 = syl[h*16 + s], aw = awl[h*16 + s];
            float x0 = floorf(x), y0 = floorf(y2);
            float xc = x0 + (float)cx, yc = y0 + (float)cy;
            int wl = WL[lvl], hl = HL[lvl];
            if (xc >= 0.f && xc <= (float)(wl-1) && yc >= 0.f && yc <= (float)(hl-1)) {
                float lx = x - x0, ly = y2 - y0;
                float wgt = aw * (cx ? lx : 1.f - lx) * (cy ? ly : 1.f - ly);
                long off = ((long)b*S_TOTAL + LS[lvl] + (int)yc*wl + (int)xc)*256 + h*32 + e*4;
                uint2 v = *(const uint2*)(value + off);
                a0 += wgt * __uint_as_float((v.x & 0xffffu) << 16);
                a1 += wgt * __uint_as_float(v.x & 0xffff0000u);
                a2 += wgt * __uint_as_float((v.y & 0xffffu) << 16);
                a3 += wgt * __uint_as_float(v.y & 0xffff0000u);
            }
        }
        #pragma unroll
        for (int o = 8; o < 64; o <<= 1) {
            a0 += __shfl_xor(a0, o); a1 += __shfl_xor(a1, o);
            a2 += __shfl_xor(a2, o); a3 += __shfl_xor(a3, o);
        }
        if (g == 0)
            *(uint2*)&sampout[row*256 + h*32 + e*4] = make_uint2(pk2(a0, a1), pk2(a2, a3));
    }
}

// ---------------- residual + layernorm (writes f32 master + bf16 copy + q) -----
__global__ void ln_kernel(float* __restrict__ prop, const float* __restrict__ delta,
                          const float* __restrict__ w, const float* __restrict__ bsh,
                          u16* __restrict__ pb_out, u16* __restrict__ q_out,
                          const float* __restrict__ ppos)
{
    int row = blockIdx.x, t = threadIdx.x;
    int lane = t & 63, wv = t >> 6;
    float v = prop[row*256 + t] + delta[row*256 + t];
    float s = v;
    for (int o = 32; o; o >>= 1) s += __shfl_xor(s, o);
    __shared__ float red[4], red2[4];
    if (lane == 0) red[wv] = s;
    __syncthreads();
    float mean = (red[0]+red[1]+red[2]+red[3]) * (1.0f/256.0f);
    float dd = v - mean;
    float s2 = dd * dd;
    for (int o = 32; o; o >>= 1) s2 += __shfl_xor(s2, o);
    if (lane == 0) red2[wv] = s2;
    __syncthreads();
    float var = (red2[0]+red2[1]+red2[2]+red2[3]) * (1.0f/256.0f);
    float nv = dd * rsqrtf(var + 1e-5f) * w[t] + bsh[t];
    prop[row*256 + t] = nv;
    pb_out[row*256 + t] = f2b(nv);
    if (q_out) q_out[row*256 + t] = f2b(nv + ppos[row*256 + t]);
}

// ---------------- qk convert: f32 -> bf16 + per-head norms ---------------------
__global__ __launch_bounds__(128) void qk_convert(
    const float* __restrict__ qkp, const float* __restrict__ kt,
    u16* __restrict__ qk_b, u16* __restrict__ kt_b,
    float* __restrict__ qn_g, float* __restrict__ knp_g, float* __restrict__ knt_g)
{
    int row = blockIdx.x, t = threadIdx.x;
    __shared__ float part[128];
    if (row < ROWS) {
        const float* sp = qkp + (long)row*512 + t*4;
        float4 v = *(const float4*)sp;
        *(uint2*)&qk_b[(long)row*512 + t*4] = make_uint2(pk2(v.x,v.y), pk2(v.z,v.w));
        part[t] = v.x*v.x + v.y*v.y + v.z*v.z + v.w*v.w;
        __syncthreads();
        if (t < 4) {
            float s = 0.f;
            for (int i = 0; i < 32; ++i) s += part[t*32 + i];
            int b = row / NQ, q = row % NQ;
            float nv = sqrtf(s) + 1e-6f;
            if      (t == 0) qn_g [(b*2+0)*NQ + q] = nv;
            else if (t == 1) qn_g [(b*2+1)*NQ + q] = nv;
            else if (t == 2) knp_g[(b*2+0)*NQ + q] = nv;
            else             knp_g[(b*2+1)*NQ + q] = nv;
        }
    } else {
        int r2 = row - ROWS;                 // 0..399
        float ss = 0.f;
        if (t < 64) {
            const float* sp = kt + (long)r2*256 + t*4;
            float4 v = *(const float4*)sp;
            *(uint2*)&kt_b[(long)r2*256 + t*4] = make_uint2(pk2(v.x,v.y), pk2(v.z,v.w));
            ss = v.x*v.x + v.y*v.y + v.z*v.z + v.w*v.w;
        }
        part[t] = ss;
        __syncthreads();
        if (t < 2) {
            float s = 0.f;
            for (int i = 0; i < 32; ++i) s += part[t*32 + i];
            int b = r2 / NTQ, qq = r2 % NTQ;
            knt_g[(b*2+t)*NTQ + qq] = sqrtf(s) + 1e-6f;
        }
    }
}

// ---------------- weight_attn via MFMA: S=Q.K^T; cos + raw logits --------------
__global__ __launch_bounds__(256) void wattn_mfma(
    const u16* __restrict__ Qb, const u16* __restrict__ Kb,
    int qstride, int kstride, int koff, int nk,
    const float* __restrict__ qn_g, const float* __restrict__ kn_g,
    float* __restrict__ out_cos, float* __restrict__ out_logit)
{
    __shared__ __align__(16) u16 As[2][128*32];
    __shared__ __align__(16) u16 Bs[2][128*32];
    int bh = blockIdx.z, b = bh >> 1, h = bh & 1;
    int tid = threadIdx.x;
    int lane = tid & 63, wave = tid >> 6;
    int bm = blockIdx.y * 128, bn = blockIdx.x * 128;
    int wm = (wave >> 1) * 64, wn = (wave & 1) * 64;
    f32x4 acc[4][4] = {};
    int r = tid >> 2, c = (tid & 3) * 8;
    const u16* Ap0 = Qb + (long)(b*NQ + min(bm + r,      NQ-1))*qstride + h*128 + c;
    const u16* Ap1 = Qb + (long)(b*NQ + min(bm + r + 64, NQ-1))*qstride + h*128 + c;
    const u16* Bp0 = Kb + (long)(b*nk + min(bn + r,      nk-1))*kstride + koff + h*128 + c;
    const u16* Bp1 = Kb + (long)(b*nk + min(bn + r + 64, nk-1))*kstride + koff + h*128 + c;
    int fr = lane & 15, fk = (lane >> 4) * 8;

    auto STG = [&](int bi, int k0) {
        ASYNC_CP16(&As[bi][tid*8],         Ap0 + k0);
        ASYNC_CP16(&As[bi][64*32 + tid*8], Ap1 + k0);
        ASYNC_CP16(&Bs[bi][tid*8],         Bp0 + k0);
        ASYNC_CP16(&Bs[bi][64*32 + tid*8], Bp1 + k0);
    };
    STG(0, 0);
    asm volatile("s_waitcnt vmcnt(0)" ::: "memory");
    __syncthreads();
    int cur = 0;
    for (int k0 = 0; k0 < 128; k0 += 32) {
        if (k0 + 32 < 128) STG(cur ^ 1, k0 + 32);
        v8bf af[4], bf[4];
        #pragma unroll
        for (int i = 0; i < 4; ++i) af[i] = *(const v8bf*)&As[cur][(wm + i*16 + fr)*32 + fk];
        #pragma unroll
        for (int j = 0; j < 4; ++j) bf[j] = *(const v8bf*)&Bs[cur][(wn + j*16 + fr)*32 + fk];
        #pragma unroll
        for (int i = 0; i < 4; ++i)
            #pragma unroll
            for (int j = 0; j < 4; ++j)
                acc[i][j] = __builtin_amdgcn_mfma_f32_16x16x32_bf16(af[i], bf[j], acc[i][j], 0, 0, 0);
        asm volatile("s_waitcnt vmcnt(0)" ::: "memory");
        __syncthreads();
        cur ^= 1;
    }
    const float SC = 0.08838834764831845f;   // 1/sqrt(128)
    int cq = lane >> 4, cn = lane & 15;
    #pragma unroll
    for (int i = 0; i < 4; ++i) {
        #pragma unroll
        for (int j = 0; j < 4; ++j) {
            int col = bn + wn + j*16 + cn;
            #pragma unroll
            for (int rr = 0; rr < 4; ++rr) {
                int m = bm + wm + i*16 + cq*4 + rr;
                if (m < NQ && col < nk) {
                    float d = acc[i][j][rr];
                    long o = ((long)(bh*NQ + m))*nk + col;
                    out_cos[o]   = d / (qn_g[bh*NQ + m] * kn_g[bh*nk + col]);
                    out_logit[o] = d * SC;
                }
            }
        }
    }
}

// ---------------- in-place row softmax over nk ---------------------------------
__global__ __launch_bounds__(64) void row_softmax(float* __restrict__ buf, int nk)
{
    long row = blockIdx.x;
    float* p = buf + row*nk;
    int lane = threadIdx.x;
    float mx = -1e30f;
    for (int k = lane; k < nk; k += 64) mx = fmaxf(mx, p[k]);
    for (int o = 32; o; o >>= 1) mx = fmaxf(mx, __shfl_xor(mx, o));
    float s = 0.f;
    for (int k = lane; k < nk; k += 64) s += expf(p[k] - mx);
    for (int o = 32; o; o >>= 1) s += __shfl_xor(s, o);
    float inv = 1.0f / s;
    for (int k = lane; k < nk; k += 64) p[k] = expf(p[k] - mx) * inv;
}

__global__ void writeout_kernel(const float* __restrict__ prop, float* __restrict__ out)
{
    int row = blockIdx.x, t = threadIdx.x;
    out[row*256 + t] = prop[row*256 + t];
}

// ---------------- host launcher ----------------
extern "C" void kernel_launch(void* const* d_in, const int* in_sizes, int n_in,
                              void* d_out, int out_size, void* d_ws, size_t ws_size,
                              hipStream_t stream)
{
    (void)in_sizes; (void)n_in; (void)out_size; (void)ws_size;
    const float* tgt  = (const float*)d_in[0];
    const float* refp = (const float*)d_in[1];
    const float* src  = (const float*)d_in[2];
    const float* svr  = (const float*)d_in[5];
    const float* Woff = (const float*)d_in[7];
    const float* boff = (const float*)d_in[8];
    const float* Wa   = (const float*)d_in[9];
    const float* ba   = (const float*)d_in[10];
    const float* Wv   = (const float*)d_in[11];
    const float* bv   = (const float*)d_in[12];
    const float* Wout = (const float*)d_in[13];
    const float* bout = (const float*)d_in[14];
    const float* Wl1  = (const float*)d_in[15];
    const float* bl1  = (const float*)d_in[16];
    const float* Wl2  = (const float*)d_in[17];
    const float* bl2  = (const float*)d_in[18];
    const float* Wq   = (const float*)d_in[19];
    const float* bq   = (const float*)d_in[20];
    const float* Wk   = (const float*)d_in[21];
    const float* bk   = (const float*)d_in[22];
    const float* n1w  = (const float*)d_in[23];
    const float* n1b  = (const float*)d_in[24];
    const float* n3w  = (const float*)d_in[25];
    const float* n3b  = (const float*)d_in[26];
    float* out = (float*)d_out;

    char* p = (char*)d_ws;
    auto alloc = [&](size_t bytes) { void* r = (void*)p; p += (bytes + 255) & ~(size_t)255; return r; };
    u16*   wt      = (u16*)  alloc(6ull*884736*2);       // 10.6 MB
    float* bias    = (float*)alloc(6ull*2688*4);
    u16*   value   = (u16*)  alloc(6ull*MVAL*256*2);     // 496 MB (all 6 layers)
    float* prop    = (float*)alloc((size_t)ROWS*256*4);
    u16*   prop_b  = (u16*)  alloc((size_t)ROWS*256*2);
    u16*   q_b     = (u16*)  alloc((size_t)ROWS*256*2);
    float* ppos    = (float*)alloc((size_t)ROWS*256*4);
    float* offatt  = (float*)alloc((size_t)ROWS*384*4);
    u16*   sampout = (u16*)  alloc((size_t)ROWS*256*2);
    float* ca      = (float*)alloc((size_t)ROWS*256*4);
    u16*   ff1     = (u16*)  alloc((size_t)ROWS*1024*2);
    float* ff2     = (float*)alloc((size_t)ROWS*256*4);
    u16*   tq      = (u16*)  alloc(400ull*256*2);
    float* qkp     = (float*)alloc((size_t)ROWS*512*4);
    float* kt      = (float*)alloc(400ull*256*4);
    u16*   qk_b    = (u16*)  alloc((size_t)ROWS*512*2);
    u16*   kt_b    = (u16*)  alloc(400ull*256*2);
    float* qn_g    = (float*)alloc(16ull*NQ*4);
    float* knp_g   = (float*)alloc(16ull*NQ*4);
    float* knt_g   = (float*)alloc(16ull*NTQ*4);

    transpose_pack<<<20799, 256, 0, stream>>>(Woff, Wa, Wv, Wout, Wl1, Wl2, Wq, Wk,
                                              boff, ba, bv, bout, bl1, bl2, bq, bk, wt, bias);
    setup_kernel<<<ROWS + 400, 256, 0, stream>>>(tgt, refp, prop, q_b, ppos, tq, out + 614400);
    // all 6 layers' value projections: register-A, zero-LDS, barrier-free;
    // reads src f32 directly (src_convert kernel + src_b buffer deleted)
    gemm_value6_v4<<<1263, 256, 0, stream>>>(src, wt, bias, value);

    for (int l = 0; l < NLAY; ++l) {
        const u16* wl_ = wt + (size_t)l*884736;
        const float* bl_ = bias + l*2688;
        gemm_bt64<<<dim3(3, 38), 256, 0, stream>>>(q_b,    wl_,          bl_,        offatt, ROWS, 384, 256, 0);
        sample_fused<<<ROWS, 256, 0, stream>>>(value + (size_t)l*MVAL*256, offatt, refp, svr, sampout);
        gemm_bt64<<<dim3(2, 38), 256, 0, stream>>>(sampout, wl_ + 163840, bl_ + 640,  ca,    ROWS, 256, 256, 0);
        ln_kernel<<<ROWS, 256, 0, stream>>>(prop, ca, n1w + l*256, n1b + l*256, prop_b, (u16*)nullptr, ppos);
        gemm_bt64<<<dim3(8, 38), 256, 0, stream>>>(prop_b, wl_ + 229376, bl_ + 896,  ff1,   ROWS, 1024, 256, 3);
        gemm_bt64<<<dim3(2, 38), 256, 0, stream>>>(ff1,    wl_ + 491520, bl_ + 1920, ff2,   ROWS, 256, 1024, 0);
        ln_kernel<<<ROWS, 256, 0, stream>>>(prop, ff2, n3w + l*256, n3b + l*256, prop_b, q_b, ppos);
    }

    const u16* w5 = wt + 5ull*884736;
    const float* b5 = bias + 5*2688;
    gemm_bt64<<<dim3(4, 38), 256, 0, stream>>>(prop_b, w5 + 753664,         b5 + 2176,       qkp, ROWS, 512, 256, 0);
    gemm_bt64<<<dim3(2, 7),  256, 0, stream>>>(tq,     w5 + 753664 + 65536, b5 + 2176 + 256, kt,  400,  256, 256, 0);
    qk_convert<<<2800, 128, 0, stream>>>(qkp, kt, qk_b, kt_b, qn_g, knp_g, knt_g);
    // pt: K from track queries (kt_b, stride 256, koff 0, nk=50)
    wattn_mfma<<<dim3(1, 3, 16), 256, 0, stream>>>(qk_b, kt_b, 512, 256, 0,   NTQ, qn_g, knt_g,
                                                   out + 624000, out + 2304000);
    // pp: K from proposals (qk_b, stride 512, koff 256, nk=300)
    wattn_mfma<<<dim3(3, 3, 16), 256, 0, stream>>>(qk_b, qk_b, 512, 512, 256, NQ,  qn_g, knp_g,
                                                   out + 864000, out + 2544000);
    row_softmax<<<4800, 64, 0, stream>>>(out + 2304000, NTQ);
    row_softmax<<<4800, 64, 0, stream>>>(out + 2544000, NQ);
    writeout_kernel<<<ROWS, 256, 0, stream>>>(prop, out);
}

// Round 7
// 1207.301 us; speedup vs baseline: 1.2520x; 1.2520x over previous
//
#include <hip/hip_runtime.h>

// ---------------- problem constants ----------------
#define BB 8
#define NQ 300
#define NTQ 50
#define NLAY 6
#define S_TOTAL 20197
#define ROWS (BB*NQ)        // 2400
#define MVAL (BB*S_TOTAL)   // 161576

typedef unsigned short u16;
typedef unsigned int u32;
typedef __bf16 v8bf __attribute__((ext_vector_type(8)));
typedef float f32x4 __attribute__((ext_vector_type(4)));

__device__ __forceinline__ u16 f2b(float f) {
    u32 u = __float_as_uint(f);
    u32 r = (u + 0x7fffu + ((u >> 16) & 1u)) >> 16;
    return (u16)r;
}
__device__ __forceinline__ u32 pk2(float lo, float hi) {
    return (u32)f2b(lo) | ((u32)f2b(hi) << 16);
}

// async global->LDS 16B/lane. LDS dest must be wave-uniform base + lane*16;
// global source address is per-lane (m173).
#define ASYNC_CP16(dst_lds, src_g) \
    __builtin_amdgcn_global_load_lds((const __attribute__((address_space(1))) u32*)(src_g), \
                                     (__attribute__((address_space(3))) u32*)(dst_lds), 16, 0, 0)

// ---------------- weight transpose (f32 -> bf16) + bias pack ----------------
// wt layout per layer (element offsets, layer stride 884736):
//   [0) offa_t 384x256 | [98304) wv_t 256x256 | [163840) wout_t 256x256
//   [229376) wl1_t 1024x256 | [491520) wl2_t 256x1024 | [753664) wqk_t 512x256
// bias f32 per layer (stride 2688): boffa[0) bv[384) bout[640) bl1[896) bl2[1920) bqk[2176)
__global__ void transpose_pack(
    const float* Woff, const float* Wa, const float* Wv, const float* Wout,
    const float* Wl1, const float* Wl2, const float* Wq, const float* Wk,
    const float* boff, const float* ba, const float* bvp, const float* bout,
    const float* bl1, const float* bl2, const float* bq, const float* bk,
    u16* wt, float* bias)
{
    int idx = blockIdx.x * 256 + threadIdx.x;
    if (idx < 5308416) {
        int l = idx / 884736;
        int o = idx % 884736;
        float v;
        if (o < 98304) { int n = o >> 8, k = o & 255;
            v = (n < 256) ? Woff[l*65536 + k*256 + n] : Wa[l*32768 + k*128 + (n-256)];
        } else if (o < 163840) { int o2 = o - 98304; int n = o2 >> 8, k = o2 & 255;
            v = Wv[l*65536 + k*256 + n];
        } else if (o < 229376) { int o2 = o - 163840; int n = o2 >> 8, k = o2 & 255;
            v = Wout[l*65536 + k*256 + n];
        } else if (o < 491520) { int o2 = o - 229376; int n = o2 >> 8, k = o2 & 255;
            v = Wl1[l*262144 + k*1024 + n];
        } else if (o < 753664) { int o2 = o - 491520; int n = o2 >> 10, k = o2 & 1023;
            v = Wl2[l*262144 + k*256 + n];
        } else { int o2 = o - 753664; int n = o2 >> 8, k = o2 & 255;
            v = (n < 256) ? Wq[l*65536 + k*256 + n] : Wk[l*65536 + k*256 + (n-256)];
        }
        wt[idx] = f2b(v);
    } else {
        int i2 = idx - 5308416;
        if (i2 < 16128) {
            int l = i2 / 2688, o = i2 % 2688;
            float v;
            if (o < 256)       v = boff[l*256 + o];
            else if (o < 384)  v = ba  [l*128 + (o-256)];
            else if (o < 640)  v = bvp [l*256 + (o-384)];
            else if (o < 896)  v = bout[l*256 + (o-640)];
            else if (o < 1920) v = bl1 [l*1024 + (o-896)];
            else if (o < 2176) v = bl2 [l*256 + (o-1920)];
            else if (o < 2432) v = bq  [l*256 + (o-2176)];
            else               v = bk  [l*256 + (o-2432)];
            bias[i2] = v;
        }
    }
}

// ---------------- setup: p_pos, proposals init, layer-0 q, p_ref out, tq pack ----
__global__ void setup_kernel(const float* tgt, const float* refp, float* prop,
                             u16* q_b, float* ppos, u16* tq, float* out_pref)
{
    int row = blockIdx.x, t = threadIdx.x;
    if (row < ROWS) {
        int b = row / NQ, q = row % NQ;
        int k = t >> 6, rem = t & 63, j = rem >> 1;
        float pr = refp[(b*350 + q)*4 + k];
        float dimt = powf(10000.0f, (float)j * (1.0f/32.0f));
        float arg = pr * 6.283185307179586f / dimt;
        float pe = (rem & 1) ? cosf(arg) : sinf(arg);
        ppos[row*256 + t] = pe;
        float pv = tgt[(b*350 + q)*256 + t];
        prop[row*256 + t] = pv;
        q_b[row*256 + t] = f2b(pv + pe);
        if (t < 4) out_pref[row*4 + t] = refp[(b*350 + q)*4 + t];
    } else {
        int r2 = row - ROWS;           // 0..399
        int b = r2 / NTQ, qq = r2 % NTQ;
        tq[r2*256 + t] = f2b(tgt[(b*350 + NQ + qq)*256 + t]);
    }
}

// ---------------- bf16 MFMA GEMM (64x128 tile, dbuf) for small-M GEMMs --------
__global__ __launch_bounds__(256) void gemm_bt64(
    const u16* __restrict__ A, const u16* __restrict__ Bt,
    const float* __restrict__ bias, void* __restrict__ Cout,
    int M, int N, int K, int flags)
{
    __shared__ __align__(16) u16 As[2][64*32];
    __shared__ __align__(16) u16 Bs[2][128*32];
    int tid = threadIdx.x;
    int lane = tid & 63, wave = tid >> 6;
    int bm = blockIdx.y * 64, bn = blockIdx.x * 128;
    int wm = (wave >> 1) * 32, wn = (wave & 1) * 64;
    f32x4 acc[2][4] = {};
    int r = tid >> 2, c = (tid & 3) * 8;
    const u16* Ap0 = A  + (long)min(bm + r,      M-1) * K + c;
    const u16* Bp0 = Bt + (long)min(bn + r,      N-1) * K + c;
    const u16* Bp1 = Bt + (long)min(bn + r + 64, N-1) * K + c;
    int fr = lane & 15, fk = (lane >> 4) * 8;

    auto STG = [&](int bi, int k0) {
        ASYNC_CP16(&As[bi][tid*8],         Ap0 + k0);
        ASYNC_CP16(&Bs[bi][tid*8],         Bp0 + k0);
        ASYNC_CP16(&Bs[bi][64*32 + tid*8], Bp1 + k0);
    };
    STG(0, 0);
    asm volatile("s_waitcnt vmcnt(0)" ::: "memory");
    __syncthreads();
    int cur = 0;
    for (int k0 = 0; k0 < K; k0 += 32) {
        if (k0 + 32 < K) STG(cur ^ 1, k0 + 32);
        v8bf af[2], bf[4];
        #pragma unroll
        for (int i = 0; i < 2; ++i) af[i] = *(const v8bf*)&As[cur][(wm + i*16 + fr)*32 + fk];
        #pragma unroll
        for (int j = 0; j < 4; ++j) bf[j] = *(const v8bf*)&Bs[cur][(wn + j*16 + fr)*32 + fk];
        #pragma unroll
        for (int i = 0; i < 2; ++i)
            #pragma unroll
            for (int j = 0; j < 4; ++j)
                acc[i][j] = __builtin_amdgcn_mfma_f32_16x16x32_bf16(af[i], bf[j], acc[i][j], 0, 0, 0);
        asm volatile("s_waitcnt vmcnt(0)" ::: "memory");
        __syncthreads();
        cur ^= 1;
    }
    int cq = lane >> 4, cn = lane & 15;
    #pragma unroll
    for (int i = 0; i < 2; ++i) {
        #pragma unroll
        for (int j = 0; j < 4; ++j) {
            int col = bn + wn + j*16 + cn;
            float bv_ = bias ? bias[col] : 0.0f;
            #pragma unroll
            for (int rr = 0; rr < 4; ++rr) {
                int m = bm + wm + i*16 + cq*4 + rr;
                if (m < M) {
                    float v = acc[i][j][rr] + bv_;
                    if (flags & 1) v = fmaxf(v, 0.0f);
                    if (flags & 2) ((u16*)Cout)[(long)m*N + col] = f2b(v);
                    else           ((float*)Cout)[(long)m*N + col] = v;
                }
            }
        }
    }
}

// ---------------- batched value GEMM v5: A-in-reg + per-tile B-LDS -------------
// value_l = src @ Wv_l^T + bv_l for l=0..5 (f32 src converted in-register;
// src_convert kernel stays deleted). Grid 1263; wave owns 32 A-rows in VGPRs
// for the whole kernel (verified v4 half). Per (layer, col-half) tile:
// barrier -> stage full 64KB B-tile into chunk-major LDS (verified v3 half,
// conflict-free ds_read_b128) -> vmcnt(0)+barrier -> 128 MFMAs/wave
// uninterrupted -> epilogue repack via WAVE-PRIVATE LDS scratch (no barrier;
// lgkmcnt+sched_barrier per rule #18) into 16B/lane stores = full 64B row
// segments (fixes the 2B-store write path). 24 barriers/block vs v3's 96.
__global__ __launch_bounds__(256, 2) void gemm_value6_v5(
    const float* __restrict__ srcf, const u16* __restrict__ wtall,
    const float* __restrict__ biasall, u16* __restrict__ Cout)
{
    __shared__ __align__(16) u16 Bsw[8*4*128*8];   // 64 KB  [ks][chunk][col][8]
    __shared__ __align__(16) u16 scr[4][16*40];    // 5 KB wave-private repack (pitch 40 u16 = 80B, 16B-aligned rows)
    int tid = threadIdx.x;
    int lane = tid & 63, wave = tid >> 6;
    int fr = lane & 15, q = lane >> 4;
    long rowb = (long)blockIdx.x * 128 + wave*32;   // wave's 32 rows

    // ---- A rows into registers (f32 -> bf16 in-reg), held for whole kernel ----
    const float* Ar0 = srcf + (long)min(rowb + fr,      (long)(MVAL-1))*256 + q*8;
    const float* Ar1 = srcf + (long)min(rowb + 16 + fr, (long)(MVAL-1))*256 + q*8;
    v8bf a0[8], a1[8];
    #pragma unroll
    for (int ks = 0; ks < 8; ++ks) {
        float4 lo = *(const float4*)(Ar0 + ks*32);
        float4 hi = *(const float4*)(Ar0 + ks*32 + 4);
        uint4 pk = make_uint4(pk2(lo.x,lo.y), pk2(lo.z,lo.w), pk2(hi.x,hi.y), pk2(hi.z,hi.w));
        a0[ks] = *(v8bf*)&pk;
        float4 lo1 = *(const float4*)(Ar1 + ks*32);
        float4 hi1 = *(const float4*)(Ar1 + ks*32 + 4);
        uint4 pk1 = make_uint4(pk2(lo1.x,lo1.y), pk2(lo1.z,lo1.w), pk2(hi1.x,hi1.y), pk2(hi1.z,hi1.w));
        a1[ks] = *(v8bf*)&pk1;
    }

    u16* myscr = &scr[wave][0];
    int rlane = lane >> 2;            // 0..15 (epilogue read row)
    int clane = (lane & 3) * 8;       // 0,8,16,24 u16 elems (16B steps)

    for (int t = 0; t < 12; ++t) {
        int z = t >> 1, half = t & 1;
        const u16* Bt = wtall + (size_t)z*884736 + 98304 + (size_t)(half*128)*256;
        if (t) __syncthreads();       // all waves done reading Bsw of tile t-1
        #pragma unroll
        for (int it = 0; it < 16; ++it) {
            int c_id = it*256 + tid;  // 0..4095 (16B chunks)
            int col = c_id & 127, chunk = (c_id >> 7) & 3, ks = c_id >> 9;
            ASYNC_CP16(&Bsw[(size_t)c_id*8], Bt + (size_t)col*256 + ks*32 + chunk*8);
        }
        asm volatile("s_waitcnt vmcnt(0)" ::: "memory");
        __syncthreads();

        u16* Cz = Cout + (size_t)z*((size_t)MVAL*256);
        const float* bs = biasall + z*2688 + 384 + half*128;

        f32x4 acc0[8] = {}, acc1[8] = {};
        #pragma unroll
        for (int ks = 0; ks < 8; ++ks) {
            v8bf bf[8];
            #pragma unroll
            for (int j = 0; j < 8; ++j)
                bf[j] = *(const v8bf*)&Bsw[ks*4096 + q*1024 + (j*16 + fr)*8];
            #pragma unroll
            for (int j = 0; j < 8; ++j) {
                acc0[j] = __builtin_amdgcn_mfma_f32_16x16x32_bf16(a0[ks], bf[j], acc0[j], 0, 0, 0);
                acc1[j] = __builtin_amdgcn_mfma_f32_16x16x32_bf16(a1[ks], bf[j], acc1[j], 0, 0, 0);
            }
        }
        // ---- epilogue: wave-private LDS repack -> 64B-contiguous row stores ----
        #pragma unroll
        for (int p = 0; p < 4; ++p) {          // column pair (j=2p, 2p+1) = 32 cols
            float blo = bs[p*32 + fr];
            float bhi = bs[p*32 + 16 + fr];
            // acc0: rows rowb+0..15
            #pragma unroll
            for (int rr = 0; rr < 4; ++rr) {
                myscr[(q*4+rr)*40 + fr]      = f2b(acc0[2*p][rr]   + blo);
                myscr[(q*4+rr)*40 + 16 + fr] = f2b(acc0[2*p+1][rr] + bhi);
            }
            asm volatile("s_waitcnt lgkmcnt(0)" ::: "memory");
            __builtin_amdgcn_sched_barrier(0);
            uint4 v0 = *(const uint4*)&myscr[rlane*40 + clane];
            asm volatile("s_waitcnt lgkmcnt(0)" ::: "memory");
            __builtin_amdgcn_sched_barrier(0);
            long g0 = rowb + rlane;
            if (g0 < MVAL)
                *(uint4*)&Cz[g0*256 + half*128 + p*32 + clane] = v0;
            // acc1: rows rowb+16..31 (reuse scratch)
            #pragma unroll
            for (int rr = 0; rr < 4; ++rr) {
                myscr[(q*4+rr)*40 + fr]      = f2b(acc1[2*p][rr]   + blo);
                myscr[(q*4+rr)*40 + 16 + fr] = f2b(acc1[2*p+1][rr] + bhi);
            }
            asm volatile("s_waitcnt lgkmcnt(0)" ::: "memory");
            __builtin_amdgcn_sched_barrier(0);
            uint4 v1 = *(const uint4*)&myscr[rlane*40 + clane];
            asm volatile("s_waitcnt lgkmcnt(0)" ::: "memory");
            __builtin_amdgcn_sched_barrier(0);
            long g1 = rowb + 16 + rlane;
            if (g1 < MVAL)
                *(uint4*)&Cz[g1*256 + half*128 + p*32 + clane] = v1;
        }
    }
}

// ---------------- fused softmax+locations (LDS) + vectorized bilinear gather ----
__global__ __launch_bounds__(256) void sample_fused(
    const u16* __restrict__ value, const float* __restrict__ offatt,
    const float* __restrict__ refp, const float* __restrict__ svr,
    u16* __restrict__ sampout)
{
    int row = blockIdx.x, t = threadIdx.x;
    int b = row / NQ, q = row % NQ;
    __shared__ float lg[128], awl[128], sxl[128], syl[128];
    const int WL[4] = {152,76,38,19}, HL[4] = {100,50,25,13}, LS[4] = {0,15200,19000,19950};

    if (t < 128) lg[t] = offatt[row*384 + 256 + t];
    __syncthreads();
    if (t < 128) {
        int h = t >> 4, s = t & 15, lvl = s >> 2, pp = s & 3;
        int gb = h << 4;
        float mx = -1e30f;
        for (int i = 0; i < 16; ++i) mx = fmaxf(mx, lg[gb + i]);
        float sm = 0.f;
        for (int i = 0; i < 16; ++i) sm += expf(lg[gb + i] - mx);
        awl[t] = expf(lg[t] - mx) / sm;
        float rx = refp[(b*350+q)*4 + 0] * svr[(b*4+lvl)*2 + 0];
        float ry = refp[(b*350+q)*4 + 1] * svr[(b*4+lvl)*2 + 1];
        float rw = refp[(b*350+q)*4 + 2] * svr[(b*4+lvl)*2 + 0];
        float rh = refp[(b*350+q)*4 + 3] * svr[(b*4+lvl)*2 + 1];
        float ox = offatt[row*384 + h*32 + lvl*8 + pp*2 + 0];
        float oy = offatt[row*384 + h*32 + lvl*8 + pp*2 + 1];
        sxl[t] = (rx + ox * 0.25f * rw * 0.5f) * (float)WL[lvl] - 0.5f;
        syl[t] = (ry + oy * 0.25f * rh * 0.5f) * (float)HL[lvl] - 0.5f;
    }
    __syncthreads();

    int lane = t & 63, wv = t >> 6;
    int g = lane >> 3, e = lane & 7;       // group handles one corner; lane -> 4 channels
    for (int hh = 0; hh < 2; ++hh) {
        int h = wv*2 + hh;
        float a0 = 0.f, a1 = 0.f, a2 = 0.f, a3 = 0.f;
        #pragma unroll
        for (int it = 0; it < 8; ++it) {
            int task = it*8 + g;           // 0..63 = s*4 + corner
            int s = task >> 2, cc = task & 3;
            int cx = cc & 1, cy = cc >> 1;
            int lvl = s >> 2;
            float x = sxl[h*16 + s], y2 = syl[h*16 + s], aw = awl[h*16 + s];
            float x0 = floorf(x), y0 = floorf(y2);
            float xc = x0 + (float)cx, yc = y0 + (float)cy;
            int wl = WL[lvl], hl = HL[lvl];
            if (xc >= 0.f && xc <= (float)(wl-1) && yc >= 0.f && yc <= (float)(hl-1)) {
                float lx = x - x0, ly = y2 - y0;
                float wgt = aw * (cx ? lx : 1.f - lx) * (cy ? ly : 1.f - ly);
                long off = ((long)b*S_TOTAL + LS[lvl] + (int)yc*wl + (int)xc)*256 + h*32 + e*4;
                uint2 v = *(const uint2*)(value + off);
                a0 += wgt * __uint_as_float((v.x & 0xffffu) << 16);
                a1 += wgt * __uint_as_float(v.x & 0xffff0000u);
                a2 += wgt * __uint_as_float((v.y & 0xffffu) << 16);
                a3 += wgt * __uint_as_float(v.y & 0xffff0000u);
            }
        }
        #pragma unroll
        for (int o = 8; o < 64; o <<= 1) {
            a0 += __shfl_xor(a0, o); a1 += __shfl_xor(a1, o);
            a2 += __shfl_xor(a2, o); a3 += __shfl_xor(a3, o);
        }
        if (g == 0)
            *(uint2*)&sampout[row*256 + h*32 + e*4] = make_uint2(pk2(a0, a1), pk2(a2, a3));
    }
}

// ---------------- residual + layernorm (writes f32 master + bf16 copy + q) -----
__global__ void ln_kernel(float* __restrict__ prop, const float* __restrict__ delta,
                          const float* __restrict__ w, const float* __restrict__ bsh,
                          u16* __restrict__ pb_out, u16* __restrict__ q_out,
                          const float* __restrict__ ppos)
{
    int row = blockIdx.x, t = threadIdx.x;
    int lane = t & 63, wv = t >> 6;
    float v = prop[row*256 + t] + delta[row*256 + t];
    float s = v;
    for (int o = 32; o; o >>= 1) s += __shfl_xor(s, o);
    __shared__ float red[4], red2[4];
    if (lane == 0) red[wv] = s;
    __syncthreads();
    float mean = (red[0]+red[1]+red[2]+red[3]) * (1.0f/256.0f);
    float dd = v - mean;
    float s2 = dd * dd;
    for (int o = 32; o; o >>= 1) s2 += __shfl_xor(s2, o);
    if (lane == 0) red2[wv] = s2;
    __syncthreads();
    float var = (red2[0]+red2[1]+red2[2]+red2[3]) * (1.0f/256.0f);
    float nv = dd * rsqrtf(var + 1e-5f) * w[t] + bsh[t];
    prop[row*256 + t] = nv;
    pb_out[row*256 + t] = f2b(nv);
    if (q_out) q_out[row*256 + t] = f2b(nv + ppos[row*256 + t]);
}

// ---------------- qk convert: f32 -> bf16 + per-head norms ---------------------
__global__ __launch_bounds__(128) void qk_convert(
    const float* __restrict__ qkp, const float* __restrict__ kt,
    u16* __restrict__ qk_b, u16* __restrict__ kt_b,
    float* __restrict__ qn_g, float* __restrict__ knp_g, float* __restrict__ knt_g)
{
    int row = blockIdx.x, t = threadIdx.x;
    __shared__ float part[128];
    if (row < ROWS) {
        const float* sp = qkp + (long)row*512 + t*4;
        float4 v = *(const float4*)sp;
        *(uint2*)&qk_b[(long)row*512 + t*4] = make_uint2(pk2(v.x,v.y), pk2(v.z,v.w));
        part[t] = v.x*v.x + v.y*v.y + v.z*v.z + v.w*v.w;
        __syncthreads();
        if (t < 4) {
            float s = 0.f;
            for (int i = 0; i < 32; ++i) s += part[t*32 + i];
            int b = row / NQ, q = row % NQ;
            float nv = sqrtf(s) + 1e-6f;
            if      (t == 0) qn_g [(b*2+0)*NQ + q] = nv;
            else if (t == 1) qn_g [(b*2+1)*NQ + q] = nv;
            else if (t == 2) knp_g[(b*2+0)*NQ + q] = nv;
            else             knp_g[(b*2+1)*NQ + q] = nv;
        }
    } else {
        int r2 = row - ROWS;                 // 0..399
        float ss = 0.f;
        if (t < 64) {
            const float* sp = kt + (long)r2*256 + t*4;
            float4 v = *(const float4*)sp;
            *(uint2*)&kt_b[(long)r2*256 + t*4] = make_uint2(pk2(v.x,v.y), pk2(v.z,v.w));
            ss = v.x*v.x + v.y*v.y + v.z*v.z + v.w*v.w;
        }
        part[t] = ss;
        __syncthreads();
        if (t < 2) {
            float s = 0.f;
            for (int i = 0; i < 32; ++i) s += part[t*32 + i];
            int b = r2 / NTQ, qq = r2 % NTQ;
            knt_g[(b*2+t)*NTQ + qq] = sqrtf(s) + 1e-6f;
        }
    }
}

// ---------------- weight_attn via MFMA: S=Q.K^T; cos + raw logits --------------
__global__ __launch_bounds__(256) void wattn_mfma(
    const u16* __restrict__ Qb, const u16* __restrict__ Kb,
    int qstride, int kstride, int koff, int nk,
    const float* __restrict__ qn_g, const float* __restrict__ kn_g,
    float* __restrict__ out_cos, float* __restrict__ out_logit)
{
    __shared__ __align__(16) u16 As[2][128*32];
    __shared__ __align__(16) u16 Bs[2][128*32];
    int bh = blockIdx.z, b = bh >> 1, h = bh & 1;
    int tid = threadIdx.x;
    int lane = tid & 63, wave = tid >> 6;
    int bm = blockIdx.y * 128, bn = blockIdx.x * 128;
    int wm = (wave >> 1) * 64, wn = (wave & 1) * 64;
    f32x4 acc[4][4] = {};
    int r = tid >> 2, c = (tid & 3) * 8;
    const u16* Ap0 = Qb + (long)(b*NQ + min(bm + r,      NQ-1))*qstride + h*128 + c;
    const u16* Ap1 = Qb + (long)(b*NQ + min(bm + r + 64, NQ-1))*qstride + h*128 + c;
    const u16* Bp0 = Kb + (long)(b*nk + min(bn + r,      nk-1))*kstride + koff + h*128 + c;
    const u16* Bp1 = Kb + (long)(b*nk + min(bn + r + 64, nk-1))*kstride + koff + h*128 + c;
    int fr = lane & 15, fk = (lane >> 4) * 8;

    auto STG = [&](int bi, int k0) {
        ASYNC_CP16(&As[bi][tid*8],         Ap0 + k0);
        ASYNC_CP16(&As[bi][64*32 + tid*8], Ap1 + k0);
        ASYNC_CP16(&Bs[bi][tid*8],         Bp0 + k0);
        ASYNC_CP16(&Bs[bi][64*32 + tid*8], Bp1 + k0);
    };
    STG(0, 0);
    asm volatile("s_waitcnt vmcnt(0)" ::: "memory");
    __syncthreads();
    int cur = 0;
    for (int k0 = 0; k0 < 128; k0 += 32) {
        if (k0 + 32 < 128) STG(cur ^ 1, k0 + 32);
        v8bf af[4], bf[4];
        #pragma unroll
        for (int i = 0; i < 4; ++i) af[i] = *(const v8bf*)&As[cur][(wm + i*16 + fr)*32 + fk];
        #pragma unroll
        for (int j = 0; j < 4; ++j) bf[j] = *(const v8bf*)&Bs[cur][(wn + j*16 + fr)*32 + fk];
        #pragma unroll
        for (int i = 0; i < 4; ++i)
            #pragma unroll
            for (int j = 0; j < 4; ++j)
                acc[i][j] = __builtin_amdgcn_mfma_f32_16x16x32_bf16(af[i], bf[j], acc[i][j], 0, 0, 0);
        asm volatile("s_waitcnt vmcnt(0)" ::: "memory");
        __syncthreads();
        cur ^= 1;
    }
    const float SC = 0.08838834764831845f;   // 1/sqrt(128)
    int cq = lane >> 4, cn = lane & 15;
    #pragma unroll
    for (int i = 0; i < 4; ++i) {
        #pragma unroll
        for (int j = 0; j < 4; ++j) {
            int col = bn + wn + j*16 + cn;
            #pragma unroll
            for (int rr = 0; rr < 4; ++rr) {
                int m = bm + wm + i*16 + cq*4 + rr;
                if (m < NQ && col < nk) {
                    float d = acc[i][j][rr];
                    long o = ((long)(bh*NQ + m))*nk + col;
                    out_cos[o]   = d / (qn_g[bh*NQ + m] * kn_g[bh*nk + col]);
                    out_logit[o] = d * SC;
                }
            }
        }
    }
}

// ---------------- in-place row softmax over nk ---------------------------------
__global__ __launch_bounds__(64) void row_softmax(float* __restrict__ buf, int nk)
{
    long row = blockIdx.x;
    float* p = buf + row*nk;
    int lane = threadIdx.x;
    float mx = -1e30f;
    for (int k = lane; k < nk; k += 64) mx = fmaxf(mx, p[k]);
    for (int o = 32; o; o >>= 1) mx = fmaxf(mx, __shfl_xor(mx, o));
    float s = 0.f;
    for (int k = lane; k < nk; k += 64) s += expf(p[k] - mx);
    for (int o = 32; o; o >>= 1) s += __shfl_xor(s, o);
    float inv = 1.0f / s;
    for (int k = lane; k < nk; k += 64) p[k] = expf(p[k] - mx) * inv;
}

__global__ void writeout_kernel(const float* __restrict__ prop, float* __restrict__ out)
{
    int row = blockIdx.x, t = threadIdx.x;
    out[row*256 + t] = prop[row*256 + t];
}

// ---------------- host launcher ----------------
extern "C" void kernel_launch(void* const* d_in, const int* in_sizes, int n_in,
                              void* d_out, int out_size, void* d_ws, size_t ws_size,
                              hipStream_t stream)
{
    (void)in_sizes; (void)n_in; (void)out_size; (void)ws_size;
    const float* tgt  = (const float*)d_in[0];
    const float* refp = (const float*)d_in[1];
    const float* src  = (const float*)d_in[2];
    const float* svr  = (const float*)d_in[5];
    const float* Woff = (const float*)d_in[7];
    const float* boff = (const float*)d_in[8];
    const float* Wa   = (const float*)d_in[9];
    const float* ba   = (const float*)d_in[10];
    const float* Wv   = (const float*)d_in[11];
    const float* bv   = (const float*)d_in[12];
    const float* Wout = (const float*)d_in[13];
    const float* bout = (const float*)d_in[14];
    const float* Wl1  = (const float*)d_in[15];
    const float* bl1  = (const float*)d_in[16];
    const float* Wl2  = (const float*)d_in[17];
    const float* bl2  = (const float*)d_in[18];
    const float* Wq   = (const float*)d_in[19];
    const float* bq   = (const float*)d_in[20];
    const float* Wk   = (const float*)d_in[21];
    const float* bk   = (const float*)d_in[22];
    const float* n1w  = (const float*)d_in[23];
    const float* n1b  = (const float*)d_in[24];
    const float* n3w  = (const float*)d_in[25];
    const float* n3b  = (const float*)d_in[26];
    float* out = (float*)d_out;

    char* p = (char*)d_ws;
    auto alloc = [&](size_t bytes) { void* r = (void*)p; p += (bytes + 255) & ~(size_t)255; return r; };
    u16*   wt      = (u16*)  alloc(6ull*884736*2);       // 10.6 MB
    float* bias    = (float*)alloc(6ull*2688*4);
    u16*   value   = (u16*)  alloc(6ull*MVAL*256*2);     // 496 MB (all 6 layers)
    float* prop    = (float*)alloc((size_t)ROWS*256*4);
    u16*   prop_b  = (u16*)  alloc((size_t)ROWS*256*2);
    u16*   q_b     = (u16*)  alloc((size_t)ROWS*256*2);
    float* ppos    = (float*)alloc((size_t)ROWS*256*4);
    float* offatt  = (float*)alloc((size_t)ROWS*384*4);
    u16*   sampout = (u16*)  alloc((size_t)ROWS*256*2);
    float* ca      = (float*)alloc((size_t)ROWS*256*4);
    u16*   ff1     = (u16*)  alloc((size_t)ROWS*1024*2);
    float* ff2     = (float*)alloc((size_t)ROWS*256*4);
    u16*   tq      = (u16*)  alloc(400ull*256*2);
    float* qkp     = (float*)alloc((size_t)ROWS*512*4);
    float* kt      = (float*)alloc(400ull*256*4);
    u16*   qk_b    = (u16*)  alloc((size_t)ROWS*512*2);
    u16*   kt_b    = (u16*)  alloc(400ull*256*2);
    float* qn_g    = (float*)alloc(16ull*NQ*4);
    float* knp_g   = (float*)alloc(16ull*NQ*4);
    float* knt_g   = (float*)alloc(16ull*NTQ*4);

    transpose_pack<<<20799, 256, 0, stream>>>(Woff, Wa, Wv, Wout, Wl1, Wl2, Wq, Wk,
                                              boff, ba, bv, bout, bl1, bl2, bq, bk, wt, bias);
    setup_kernel<<<ROWS + 400, 256, 0, stream>>>(tgt, refp, prop, q_b, ppos, tq, out + 614400);
    // all 6 layers' value projections: A-in-reg + per-tile B-LDS + coalesced C
    gemm_value6_v5<<<1263, 256, 0, stream>>>(src, wt, bias, value);

    for (int l = 0; l < NLAY; ++l) {
        const u16* wl_ = wt + (size_t)l*884736;
        const float* bl_ = bias + l*2688;
        gemm_bt64<<<dim3(3, 38), 256, 0, stream>>>(q_b,    wl_,          bl_,        offatt, ROWS, 384, 256, 0);
        sample_fused<<<ROWS, 256, 0, stream>>>(value + (size_t)l*MVAL*256, offatt, refp, svr, sampout);
        gemm_bt64<<<dim3(2, 38), 256, 0, stream>>>(sampout, wl_ + 163840, bl_ + 640,  ca,    ROWS, 256, 256, 0);
        ln_kernel<<<ROWS, 256, 0, stream>>>(prop, ca, n1w + l*256, n1b + l*256, prop_b, (u16*)nullptr, ppos);
        gemm_bt64<<<dim3(8, 38), 256, 0, stream>>>(prop_b, wl_ + 229376, bl_ + 896,  ff1,   ROWS, 1024, 256, 3);
        gemm_bt64<<<dim3(2, 38), 256, 0, stream>>>(ff1,    wl_ + 491520, bl_ + 1920, ff2,   ROWS, 256, 1024, 0);
        ln_kernel<<<ROWS, 256, 0, stream>>>(prop, ff2, n3w + l*256, n3b + l*256, prop_b, q_b, ppos);
    }

    const u16* w5 = wt + 5ull*884736;
    const float* b5 = bias + 5*2688;
    gemm_bt64<<<dim3(4, 38), 256, 0, stream>>>(prop_b, w5 + 753664,         b5 + 2176,       qkp, ROWS, 512, 256, 0);
    gemm_bt64<<<dim3(2, 7),  256, 0, stream>>>(tq,     w5 + 753664 + 65536, b5 + 2176 + 256, kt,  400,  256, 256, 0);
    qk_convert<<<2800, 128, 0, stream>>>(qkp, kt, qk_b, kt_b, qn_g, knp_g, knt_g);
    // pt: K from track queries (kt_b, stride 256, koff 0, nk=50)
    wattn_mfma<<<dim3(1, 3, 16), 256, 0, stream>>>(qk_b, kt_b, 512, 256, 0,   NTQ, qn_g, knt_g,
                                                   out + 624000, out + 2304000);
    // pp: K from proposals (qk_b, stride 512, koff 256, nk=300)
    wattn_mfma<<<dim3(3, 3, 16), 256, 0, stream>>>(qk_b, qk_b, 512, 512, 256, NQ,  qn_g, knp_g,
                                                   out + 864000, out + 2544000);
    row_softmax<<<4800, 64, 0, stream>>>(out + 2304000, NTQ);
    row_softmax<<<4800, 64, 0, stream>>>(out + 2544000, NQ);
    writeout_kernel<<<ROWS, 256, 0, stream>>>(prop, out);
}